// Round 15
// baseline (325.011 us; speedup 1.0000x reference)
//
#include <hip/hip_runtime.h>
#include <math.h>

#define D_M 1024
#define S_L 8192
#define B_N 8
#define H_N 8
#define HD_ 128
#define HK_ 64
#define SCALE_ 0.08838834764831845f
#define NEG_INF_ -1e9f
#define PITCH_ 40   // k_part transposed tile pitch (halves): 80B, 16B-aligned
#define AP_ 72      // k_scores3 As/Bs pitch (halves): 144B -> balanced banks, 16B-aligned

typedef _Float16 half8v __attribute__((ext_vector_type(8)));
typedef _Float16 half4v __attribute__((ext_vector_type(4)));
typedef float floatx4 __attribute__((ext_vector_type(4)));

// ---- q[kidx][i] = latent[kidx] . Wq[i] + bq[i]   (8x1024)
__global__ void k_q(const float* __restrict__ lat, const float* __restrict__ W,
                    const float* __restrict__ bias, float* __restrict__ q) {
  int g = blockIdx.x * blockDim.x + threadIdx.x;          // 8192
  int kidx = g >> 10, i = g & 1023;
  const float* wr = W + (size_t)i * D_M;
  const float* lr = lat + kidx * D_M;
  float acc = bias[i];
  #pragma unroll 4
  for (int t = 0; t < D_M; t += 4) {
    float4 w = *(const float4*)(wr + t);
    float4 l = *(const float4*)(lr + t);
    acc += w.x*l.x + w.y*l.y + w.z*l.z + w.w*l.w;
  }
  q[g] = acc;
}

// ---- qth[hk][j] = fp16( SCALE * sum_dd q[kidx][h*128+dd] * Wk[h*128+dd][j] ); qconst[hk]
__global__ void k_qt(const float* __restrict__ q, const float* __restrict__ W,
                     const float* __restrict__ bias, _Float16* __restrict__ qth,
                     float* __restrict__ qconst) {
  int g = blockIdx.x * blockDim.x + threadIdx.x;          // 65536
  int hk = g >> 10, j = g & 1023;
  int h = hk >> 3, kidx = hk & 7;
  const float* qr = q + kidx * D_M + h * HD_;
  const float* wb = W + ((size_t)D_M + (size_t)h * HD_) * D_M + j;
  float acc = 0.f;
  #pragma unroll 4
  for (int dd = 0; dd < HD_; ++dd)
    acc += qr[dd] * wb[(size_t)dd * D_M];
  qth[g] = (_Float16)(acc * SCALE_);
  if (j == 0) {
    const float* bk = bias + D_M + h * HD_;
    float c = 0.f;
    for (int dd = 0; dd < HD_; ++dd) c += qr[dd] * bk[dd];
    qconst[hk] = c * SCALE_;
  }
}

// ---- per b: compact row map ridx[b][slot] = orig s (stable order), cnt[b].
// grid 8, block 512. Deterministic. Pad slots -> 0 (finite data, ph=0 kills them).
__global__ __launch_bounds__(512) void k_cnt(const int* __restrict__ mask,
                                             int* __restrict__ ridx,
                                             int* __restrict__ cnt) {
  __shared__ int wsum[8];
  __shared__ int base_s;
  int b = blockIdx.x, tid = threadIdx.x, w = tid >> 6, lane = tid & 63;
  #pragma unroll
  for (int it = 0; it < 16; ++it) ridx[b * S_L + it * 512 + tid] = 0;
  if (tid == 0) base_s = 0;
  __syncthreads();
  for (int it = 0; it < 16; ++it) {
    int s = it * 512 + tid;
    int valid = mask[b * S_L + s] != 0;
    unsigned long long m = __ballot(valid);
    int rank = __popcll(m & ((1ull << lane) - 1ull));
    if (lane == 0) wsum[w] = __popcll(m);
    __syncthreads();                       // wsum ready
    int base = base_s;
    int woff = 0, ctot = 0;
    #pragma unroll
    for (int i = 0; i < 8; ++i) { if (i < w) woff += wsum[i]; ctot += wsum[i]; }
    __syncthreads();                       // all read base_s
    if (valid) ridx[b * S_L + base + woff + rank] = s;
    if (tid == 0) base_s = base + ctot;
    __syncthreads();                       // base_s updated
  }
  if (tid == 0) cnt[b] = base_s;
}

// ---- QK^T via MFMA on COMPACT rows (indirect stage through ridx), 64-row tiles, BK=64.
//      Side-writes fp16 compact h16c; emits ph = exp(v - m_tile16), pm/pl.
// grid 1024 = b(8) x st(128 of 64 rows); block 256 (4 waves, wave = 16 rows x 64 hk).
__global__ __launch_bounds__(256) void k_scores3(
    const float* __restrict__ hsrc, const _Float16* __restrict__ qth,
    const float* __restrict__ qc, const int* __restrict__ cnt,
    const int* __restrict__ ridx, _Float16* __restrict__ h16c,
    _Float16* __restrict__ ph, float* __restrict__ pm, float* __restrict__ pl) {
  __shared__ __align__(16) _Float16 As[64 * AP_];    // 9 KB
  __shared__ __align__(16) _Float16 Bs[64 * AP_];    // 9 KB
  __shared__ _Float16 pT[64][68];                    // 8.7 KB (transpose buffer)
  __shared__ float qcs[64];
  __shared__ int ridx_s[64];
  const int tid = threadIdx.x;
  const int b = blockIdx.x >> 7;
  const int st = blockIdx.x & 127;
  const int s0 = st * 64;
  const int cb = cnt[b];
  const int SPb = ((cb + 511) >> 9) << 9;
  if (s0 >= SPb) return;                             // uniform early exit
  const int w = tid >> 6, l = tid & 63;
  const int row16 = l & 15, kc = l >> 4;
  if (tid < 64) qcs[tid] = qc[tid];
  if (tid < 64) ridx_s[tid] = ridx[b * S_L + s0 + tid];
  floatx4 acc[4];
  #pragma unroll
  for (int nf = 0; nf < 4; ++nf) acc[nf] = (floatx4){0.f, 0.f, 0.f, 0.f};

  const int r_ = tid >> 3, c_ = tid & 7;             // stage: 2 A-rows + 2 B-rows, slot c_
  __syncthreads();                                   // ridx_s ready
  const float* rowp[2];
  _Float16* h16p[2];
  #pragma unroll
  for (int p = 0; p < 2; ++p) {
    rowp[p] = hsrc + ((size_t)b * S_L + ridx_s[p * 32 + r_]) * D_M + c_ * 8;
    h16p[p] = h16c + ((size_t)b * S_L + s0 + p * 32 + r_) * D_M + c_ * 8;
  }
  float4 fa[2][2];
  half8v fb[2];
  #pragma unroll
  for (int p = 0; p < 2; ++p) {
    fa[p][0] = *(const float4*)rowp[p]; fa[p][1] = *(const float4*)(rowp[p] + 4);
  }
  fb[0] = *(const half8v*)(qth + (size_t)r_ * D_M + c_ * 8);
  fb[1] = *(const half8v*)(qth + (size_t)(r_ + 32) * D_M + c_ * 8);

  for (int k0 = 0; k0 < D_M; k0 += 64) {
    __syncthreads();
    #pragma unroll
    for (int p = 0; p < 2; ++p) {
      half8v hv;
      hv[0] = (_Float16)fa[p][0].x; hv[1] = (_Float16)fa[p][0].y;
      hv[2] = (_Float16)fa[p][0].z; hv[3] = (_Float16)fa[p][0].w;
      hv[4] = (_Float16)fa[p][1].x; hv[5] = (_Float16)fa[p][1].y;
      hv[6] = (_Float16)fa[p][1].z; hv[7] = (_Float16)fa[p][1].w;
      *(half8v*)&As[(p * 32 + r_) * AP_ + c_ * 8] = hv;
      *(half8v*)(h16p[p] + k0) = hv;                 // fp16 compact side-write
    }
    *(half8v*)&Bs[r_ * AP_ + c_ * 8] = fb[0];
    *(half8v*)&Bs[(r_ + 32) * AP_ + c_ * 8] = fb[1];
    if (k0 + 64 < D_M) {
      #pragma unroll
      for (int p = 0; p < 2; ++p) {
        fa[p][0] = *(const float4*)(rowp[p] + k0 + 64);
        fa[p][1] = *(const float4*)(rowp[p] + k0 + 64 + 4);
      }
      fb[0] = *(const half8v*)(qth + (size_t)r_ * D_M + (k0 + 64) + c_ * 8);
      fb[1] = *(const half8v*)(qth + (size_t)(r_ + 32) * D_M + (k0 + 64) + c_ * 8);
    }
    __syncthreads();
    #pragma unroll
    for (int kk = 0; kk < 2; ++kk) {
      half8v af = *(const half8v*)&As[(w * 16 + row16) * AP_ + kk * 32 + kc * 8];
      #pragma unroll
      for (int nf = 0; nf < 4; ++nf) {
        half8v bf = *(const half8v*)&Bs[(nf * 16 + row16) * AP_ + kk * 32 + kc * 8];
        acc[nf] = __builtin_amdgcn_mfma_f32_16x16x32_f16(af, bf, acc[nf], 0, 0, 0);
      }
    }
  }
  // ---- epilogue: valid = compact row < cnt[b]; 16-row tile max, exp into pT, pm/pl
  int msk[4];
  #pragma unroll
  for (int r = 0; r < 4; ++r)
    msk[r] = (s0 + w * 16 + kc * 4 + r) < cb;
  #pragma unroll
  for (int nf = 0; nf < 4; ++nf) {
    int hk = nf * 16 + row16;
    float qcv = qcs[hk];
    float vals[4];
    float mloc = -3.4e38f;
    #pragma unroll
    for (int r = 0; r < 4; ++r) {
      float v = msk[r] ? (acc[nf][r] + qcv) : NEG_INF_;
      vals[r] = v;
      mloc = fmaxf(mloc, v);
    }
    mloc = fmaxf(mloc, __shfl_xor(mloc, 16, 64));
    mloc = fmaxf(mloc, __shfl_xor(mloc, 32, 64));
    float ls = 0.f;
    #pragma unroll
    for (int r = 0; r < 4; ++r) {
      float e = __expf(vals[r] - mloc);
      ls += e;
      pT[w * 16 + kc * 4 + r][hk] = (_Float16)e;
    }
    ls += __shfl_xor(ls, 16, 64);
    ls += __shfl_xor(ls, 32, 64);
    if (kc == 0) {
      int idx = ((b * 512) + st * 4 + w) * 64 + hk;  // tile = st*4+w (16 rows)
      pm[idx] = mloc;
      pl[idx] = ls;
    }
  }
  __syncthreads();
  // ---- coalesced ph write: thread = (hk2, s-quarter of 16)
  {
    int hk2 = tid >> 2, q4 = tid & 3;
    _Float16* dst = ph + ((size_t)b * 64 + hk2) * S_L + s0 + q4 * 16;
    #pragma unroll
    for (int i = 0; i < 2; ++i) {
      half8v v;
      #pragma unroll
      for (int e = 0; e < 8; ++e) v[e] = pT[q4 * 16 + i * 8 + e][hk2];
      *(half8v*)(dst + i * 8) = v;
    }
  }
}

// ---- per (b,hk): reduce valid 16-row tile partials -> lvinv; rescale ph by exp(m - M)
// grid 512 = b*64+hk; block 512 (thread = tile of 16 rows)
__global__ __launch_bounds__(512) void k_stats2b(
    const float* __restrict__ pm, const float* __restrict__ pl,
    const int* __restrict__ cnt, float* __restrict__ lvinv, _Float16* __restrict__ ph) {
  __shared__ float red[512];
  int bh = blockIdx.x;
  int b = bh >> 6, hk = bh & 63;
  int tid = threadIdx.x;
  const int cb = cnt[b];
  const int ntile = (((cb + 511) >> 9) << 9) >> 4;   // SPb/16
  float m = -3.4e38f, lv = 0.f;
  if (tid < ntile) {
    m = pm[((size_t)b * 512 + tid) * 64 + hk];
    lv = pl[((size_t)b * 512 + tid) * 64 + hk];
  }
  red[tid] = m; __syncthreads();
  for (int off = 256; off > 0; off >>= 1) {
    if (tid < off) red[tid] = fmaxf(red[tid], red[tid + off]);
    __syncthreads();
  }
  float M = red[0]; __syncthreads();
  red[tid] = lv * __expf(m - M); __syncthreads();
  for (int off = 256; off > 0; off >>= 1) {
    if (tid < off) red[tid] += red[tid + off];
    __syncthreads();
  }
  if (tid == 0) lvinv[bh] = 1.f / red[0];
  if (tid < ntile) {
    float f = __expf(m - M);
    _Float16* pp = ph + (size_t)bh * S_L + tid * 16;
    #pragma unroll
    for (int i = 0; i < 2; ++i) {
      half8v v = *(half8v*)(pp + i * 8);
      #pragma unroll
      for (int e = 0; e < 8; ++e) v[e] = (_Float16)((float)v[e] * f);
      *(half8v*)(pp + i * 8) = v;
    }
  }
}

// ---- PV via MFMA on COMPACT fp16 rows: part[b][jb][sc][hk][512], sc chunks of 256
// grid 512 = b(8) x jb(2) x sc(32 of 256 s); block 512 (8 waves). Early-exit past SPb.
__global__ __launch_bounds__(512) void k_part(
    const _Float16* __restrict__ h16c, const _Float16* __restrict__ ph,
    const int* __restrict__ cnt, float* __restrict__ part) {
  __shared__ __align__(16) _Float16 htile[512 * PITCH_];   // 40 KB
  const int tid = threadIdx.x;
  const int b  = blockIdx.x >> 6;
  const int jb = (blockIdx.x >> 5) & 1;
  const int sc = blockIdx.x & 31;
  const int SPb = ((cnt[b] + 511) >> 9) << 9;
  if (sc * 256 >= SPb) return;                       // uniform early exit
  const int w = tid >> 6, l = tid & 63;
  const int row16 = l & 15, kc = l >> 4;
  const int s_base = sc * 256;
  const _Float16* hb = h16c + (size_t)b * S_L * D_M + jb * 512;
  const _Float16* phb = ph + (size_t)b * HK_ * S_L;
  floatx4 acc[4][4];
  #pragma unroll
  for (int mf = 0; mf < 4; ++mf)
    #pragma unroll
    for (int nf = 0; nf < 4; ++nf) acc[mf][nf] = (floatx4){0.f, 0.f, 0.f, 0.f};

  const int jcol = tid;
  _Float16 colv[32];
  #pragma unroll
  for (int s = 0; s < 32; ++s)
    colv[s] = hb[(size_t)(s_base + s) * D_M + jcol];

  for (int t = 0; t < 8; ++t) {
    const int s0 = s_base + t * 32;
    __syncthreads();
    #pragma unroll
    for (int sb = 0; sb < 8; ++sb) {
      half4v hv;
      hv[0] = colv[sb * 4 + 0];
      hv[1] = colv[sb * 4 + 1];
      hv[2] = colv[sb * 4 + 2];
      hv[3] = colv[sb * 4 + 3];
      *(half4v*)&htile[jcol * PITCH_ + sb * 4] = hv;
    }
    __syncthreads();
    if (t < 7) {
      #pragma unroll
      for (int s = 0; s < 32; ++s)
        colv[s] = hb[(size_t)(s0 + 32 + s) * D_M + jcol];
    }
    half8v ap[4];
    #pragma unroll
    for (int mf = 0; mf < 4; ++mf)
      ap[mf] = *(const half8v*)(phb + (size_t)(mf * 16 + row16) * S_L + s0 + kc * 8);
    #pragma unroll
    for (int nf = 0; nf < 4; ++nf) {
      int j = w * 64 + nf * 16 + row16;
      half8v bv = *(const half8v*)&htile[j * PITCH_ + kc * 8];
      #pragma unroll
      for (int mf = 0; mf < 4; ++mf)
        acc[mf][nf] = __builtin_amdgcn_mfma_f32_16x16x32_f16(ap[mf], bv, acc[mf][nf], 0, 0, 0);
    }
  }
  #pragma unroll
  for (int mf = 0; mf < 4; ++mf)
    #pragma unroll
    for (int nf = 0; nf < 4; ++nf) {
      int j = w * 64 + nf * 16 + row16;
      #pragma unroll
      for (int r = 0; r < 4; ++r) {
        int hk = mf * 16 + kc * 4 + r;
        part[(((size_t)(b * 2 + jb) * 32 + sc) * HK_ + hk) * 512 + j] = acc[mf][nf][r];
      }
    }
}

// ---- ctxh[b][hk][j] = (sum over valid sc) part * lvinv
__global__ void k_comb(const float* __restrict__ part, const float* __restrict__ lvinv,
                       const int* __restrict__ cnt, float* __restrict__ ctxh) {
  int g = blockIdx.x * blockDim.x + threadIdx.x;  // 131072 float4s
  int b = g >> 14;
  int rem = g & 16383;
  int hk = rem >> 8;
  int j4 = rem & 255;
  int jb = j4 >> 7;
  int jr4 = j4 & 127;
  const int nsc = (((cnt[b] + 511) >> 9) << 9) >> 8;   // SPb/256
  const float* pb = part + ((size_t)(b * 2 + jb) * 32 * HK_ + hk) * 512 + jr4 * 4;
  float4 s = make_float4(0.f, 0.f, 0.f, 0.f);
  for (int sc = 0; sc < nsc; ++sc) {
    float4 v = *(const float4*)(pb + (size_t)sc * HK_ * 512);
    s.x += v.x; s.y += v.y; s.z += v.z; s.w += v.w;
  }
  float li = lvinv[b * 64 + hk];
  s.x *= li; s.y *= li; s.z *= li; s.w *= li;
  *(float4*)(ctxh + ((size_t)b * HK_ + hk) * D_M + j4 * 4) = s;
}

// ---- ctx[b][kidx][i] = Wv[i].ctxh[b][hk(i,kidx)] + bv[i]  (4-way split-K)
__global__ void k_ctx(const float* __restrict__ ctxh, const float* __restrict__ W,
                      const float* __restrict__ bias, float* __restrict__ ctx) {
  int g2 = blockIdx.x * blockDim.x + threadIdx.x;   // 262144
  int o = g2 >> 2, kq = g2 & 3;
  int b = o >> 13, kidx = (o >> 10) & 7, i = o & 1023;
  int hk = (i >> 7) * 8 + kidx;
  const float* wr = W + ((size_t)2 * D_M + i) * D_M + kq * 256;
  const float* xr = ctxh + ((size_t)b * HK_ + hk) * D_M + kq * 256;
  float acc = 0.f;
  #pragma unroll 8
  for (int t = 0; t < 256; t += 4) {
    float4 w = *(const float4*)(wr + t);
    float4 x = *(const float4*)(xr + t);
    acc += w.x*x.x + w.y*x.y + w.z*x.z + w.w*x.w;
  }
  acc += __shfl_xor(acc, 1, 64);
  acc += __shfl_xor(acc, 2, 64);
  if (kq == 0) ctx[o] = acc + bias[2 * D_M + i];
}

// ---- pooled[b][kidx][i] = Wout[i].ctx[b][kidx] + bo[i]  (4-way split-K)
__global__ void k_pool(const float* __restrict__ ctx, const float* __restrict__ W,
                       const float* __restrict__ bias, float* __restrict__ pooled) {
  int g2 = blockIdx.x * blockDim.x + threadIdx.x;   // 262144
  int o = g2 >> 2, kq = g2 & 3;
  int b = o >> 13, kidx = (o >> 10) & 7, i = o & 1023;
  const float* wr = W + (size_t)i * D_M + kq * 256;
  const float* xr = ctx + ((size_t)b * 8 + kidx) * D_M + kq * 256;
  float acc = 0.f;
  #pragma unroll 8
  for (int t = 0; t < 256; t += 4) {
    float4 w = *(const float4*)(wr + t);
    float4 x = *(const float4*)(xr + t);
    acc += w.x*x.x + w.y*x.y + w.z*x.z + w.w*x.w;
  }
  acc += __shfl_xor(acc, 1, 64);
  acc += __shfl_xor(acc, 2, 64);
  if (kq == 0) pooled[o] = acc + bias[i];
}

// ---- LayerNorm per (b,kidx) then mean over kidx -> out[b][i]
__global__ void k_ln(const float* __restrict__ pooled, const float* __restrict__ gamma,
                     const float* __restrict__ beta, float* __restrict__ out) {
  __shared__ float red[256];
  int b = blockIdx.x, tid = threadIdx.x;
  float acc[4] = {0.f, 0.f, 0.f, 0.f};
  for (int kidx = 0; kidx < 8; ++kidx) {
    const float* row = pooled + ((size_t)b * 8 + kidx) * D_M;
    float v[4]; float s = 0.f;
    #pragma unroll
    for (int c = 0; c < 4; ++c) { v[c] = row[tid + 256 * c]; s += v[c]; }
    red[tid] = s; __syncthreads();
    for (int off = 128; off > 0; off >>= 1) {
      if (tid < off) red[tid] += red[tid + off];
      __syncthreads();
    }
    float mu = red[0] * (1.f / 1024.f);
    __syncthreads();
    float ss = 0.f;
    #pragma unroll
    for (int c = 0; c < 4; ++c) { float dd = v[c] - mu; ss += dd * dd; }
    red[tid] = ss; __syncthreads();
    for (int off = 128; off > 0; off >>= 1) {
      if (tid < off) red[tid] += red[tid + off];
      __syncthreads();
    }
    float rstd = rsqrtf(red[0] * (1.f / 1024.f) + 1e-5f);
    __syncthreads();
    #pragma unroll
    for (int c = 0; c < 4; ++c) {
      int i = tid + 256 * c;
      acc[c] += ((v[c] - mu) * rstd * gamma[i] + beta[i]) * 0.125f;
    }
  }
  #pragma unroll
  for (int c = 0; c < 4; ++c) out[(size_t)b * D_M + tid + 256 * c] = acc[c];
}

extern "C" void kernel_launch(void* const* d_in, const int* in_sizes, int n_in,
                              void* d_out, int out_size, void* d_ws, size_t ws_size,
                              hipStream_t stream) {
  const float* hidden = (const float*)d_in[0];
  const float* latent = (const float*)d_in[1];
  const float* w_in   = (const float*)d_in[2];
  const float* b_in   = (const float*)d_in[3];
  const float* w_out  = (const float*)d_in[4];
  const float* b_out  = (const float*)d_in[5];
  const float* gamma  = (const float*)d_in[6];
  const float* beta   = (const float*)d_in[7];
  const int*   mask   = (const int*)d_in[8];
  float* out = (float*)d_out;
  float* ws = (float*)d_ws;
  // workspace layout (floats): ~215 MB total
  float* q      = ws;                       // 8192
  float* qc     = q + 8192;                 // 64
  float* lvinv  = qc + 64;                  // 512
  float* pm     = lvinv + 512;              // 262144 = [8][512][64]
  float* pl     = pm + 262144;              // 262144
  _Float16* qth = (_Float16*)(pl + 262144);          // 65536 halves (32768 float slots)
  _Float16* ph  = (_Float16*)(pl + 262144 + 32768);  // 4194304 halves (2097152 slots)
  float* part   = pl + 262144 + 32768 + 2097152;     // 16777216 = [8][2][32][64][512]
  float* ctxh   = part + 16777216;          // 524288
  float* ctx    = ctxh + 524288;            // 65536
  float* pooled = ctx + 65536;              // 65536
  int*   cnt    = (int*)(pooled + 65536);   // 16 ints
  int*   ridx   = (int*)(pooled + 65536 + 16);        // 65536 ints
  _Float16* h16c = (_Float16*)(pooled + 65536 + 16 + 65536);  // 67108864 halves (128 MB)

  k_q       <<<32,   256, 0, stream>>>(latent, w_in, b_in, q);
  k_qt      <<<256,  256, 0, stream>>>(q, w_in, b_in, qth, qc);
  k_cnt     <<<8,    512, 0, stream>>>(mask, ridx, cnt);
  k_scores3 <<<1024, 256, 0, stream>>>(hidden, qth, qc, cnt, ridx, h16c, ph, pm, pl);
  k_stats2b <<<512,  512, 0, stream>>>(pm, pl, cnt, lvinv, ph);
  k_part    <<<512,  512, 0, stream>>>(h16c, ph, cnt, part);
  k_comb    <<<512,  256, 0, stream>>>(part, lvinv, cnt, ctxh);
  k_ctx     <<<1024, 256, 0, stream>>>(ctxh, w_in, b_in, ctx);
  k_pool    <<<1024, 256, 0, stream>>>(ctx, w_out, b_out, pooled);
  k_ln      <<<8,    256, 0, stream>>>(pooled, gamma, beta, out);
}

// Round 16
// 324.622 us; speedup vs baseline: 1.0012x; 1.0012x over previous
//
#include <hip/hip_runtime.h>
#include <math.h>

#define D_M 1024
#define S_L 8192
#define B_N 8
#define H_N 8
#define HD_ 128
#define HK_ 64
#define SCALE_ 0.08838834764831845f
#define NEG_INF_ -1e9f
#define PITCH_ 40   // k_part transposed tile pitch (halves): 80B, 16B-aligned
#define AP_ 72      // k_scores3 As/Bs pitch (halves): 144B -> balanced banks, 16B-aligned

typedef _Float16 half8v __attribute__((ext_vector_type(8)));
typedef _Float16 half4v __attribute__((ext_vector_type(4)));
typedef float floatx4 __attribute__((ext_vector_type(4)));

// ---- q[kidx][i] = latent[kidx] . Wq[i] + bq[i]   (8x1024)
__global__ void k_q(const float* __restrict__ lat, const float* __restrict__ W,
                    const float* __restrict__ bias, float* __restrict__ q) {
  int g = blockIdx.x * blockDim.x + threadIdx.x;          // 8192
  int kidx = g >> 10, i = g & 1023;
  const float* wr = W + (size_t)i * D_M;
  const float* lr = lat + kidx * D_M;
  float acc = bias[i];
  #pragma unroll 4
  for (int t = 0; t < D_M; t += 4) {
    float4 w = *(const float4*)(wr + t);
    float4 l = *(const float4*)(lr + t);
    acc += w.x*l.x + w.y*l.y + w.z*l.z + w.w*l.w;
  }
  q[g] = acc;
}

// ---- qth[hk][j] = fp16( SCALE * sum_dd q[kidx][h*128+dd] * Wk[h*128+dd][j] ); qconst[hk]
__global__ void k_qt(const float* __restrict__ q, const float* __restrict__ W,
                     const float* __restrict__ bias, _Float16* __restrict__ qth,
                     float* __restrict__ qconst) {
  int g = blockIdx.x * blockDim.x + threadIdx.x;          // 65536
  int hk = g >> 10, j = g & 1023;
  int h = hk >> 3, kidx = hk & 7;
  const float* qr = q + kidx * D_M + h * HD_;
  const float* wb = W + ((size_t)D_M + (size_t)h * HD_) * D_M + j;
  float acc = 0.f;
  #pragma unroll 4
  for (int dd = 0; dd < HD_; ++dd)
    acc += qr[dd] * wb[(size_t)dd * D_M];
  qth[g] = (_Float16)(acc * SCALE_);
  if (j == 0) {
    const float* bk = bias + D_M + h * HD_;
    float c = 0.f;
    for (int dd = 0; dd < HD_; ++dd) c += qr[dd] * bk[dd];
    qconst[hk] = c * SCALE_;
  }
}

// ---- per b: compact row map ridx[b][slot] = orig s (stable order), cnt[b].
// grid 8, block 512. Deterministic. Pad slots -> 0 (finite data, ph=0 kills them).
__global__ __launch_bounds__(512) void k_cnt(const int* __restrict__ mask,
                                             int* __restrict__ ridx,
                                             int* __restrict__ cnt) {
  __shared__ int wsum[8];
  __shared__ int base_s;
  int b = blockIdx.x, tid = threadIdx.x, w = tid >> 6, lane = tid & 63;
  #pragma unroll
  for (int it = 0; it < 16; ++it) ridx[b * S_L + it * 512 + tid] = 0;
  if (tid == 0) base_s = 0;
  __syncthreads();
  for (int it = 0; it < 16; ++it) {
    int s = it * 512 + tid;
    int valid = mask[b * S_L + s] != 0;
    unsigned long long m = __ballot(valid);
    int rank = __popcll(m & ((1ull << lane) - 1ull));
    if (lane == 0) wsum[w] = __popcll(m);
    __syncthreads();                       // wsum ready
    int base = base_s;
    int woff = 0, ctot = 0;
    #pragma unroll
    for (int i = 0; i < 8; ++i) { if (i < w) woff += wsum[i]; ctot += wsum[i]; }
    __syncthreads();                       // all read base_s
    if (valid) ridx[b * S_L + base + woff + rank] = s;
    if (tid == 0) base_s = base + ctot;
    __syncthreads();                       // base_s updated
  }
  if (tid == 0) cnt[b] = base_s;
}

// ---- QK^T via MFMA on COMPACT rows (indirect stage through ridx), BK=64.
//      Side-writes fp16 compact h16c; emits ph = exp(v - m_tile32), pm/pl.
// grid 512 = b(8) x st(64 of 128 rows); block 256 (4 waves). Early-exit past SPb.
__global__ __launch_bounds__(256) void k_scores3(
    const float* __restrict__ hsrc, const _Float16* __restrict__ qth,
    const float* __restrict__ qc, const int* __restrict__ cnt,
    const int* __restrict__ ridx, _Float16* __restrict__ h16c,
    _Float16* __restrict__ ph, float* __restrict__ pm, float* __restrict__ pl) {
  __shared__ __align__(16) _Float16 As[128 * AP_];   // 18 KB
  __shared__ __align__(16) _Float16 Bs[64 * AP_];    // 9 KB
  __shared__ _Float16 pT[128][68];                   // 17 KB (transpose buffer)
  __shared__ float qcs[64];
  __shared__ int ridx_s[128];
  const int tid = threadIdx.x;
  const int b = blockIdx.x >> 6;
  const int st = blockIdx.x & 63;
  const int s0 = st * 128;
  const int cb = cnt[b];
  const int SPb = ((cb + 511) >> 9) << 9;
  if (s0 >= SPb) return;                             // uniform early exit
  const int w = tid >> 6, l = tid & 63;
  const int row16 = l & 15, kc = l >> 4;
  if (tid < 64) qcs[tid] = qc[tid];
  if (tid < 128) ridx_s[tid] = ridx[b * S_L + s0 + tid];
  floatx4 acc[2][4];
  #pragma unroll
  for (int mf = 0; mf < 2; ++mf)
    #pragma unroll
    for (int nf = 0; nf < 4; ++nf) acc[mf][nf] = (floatx4){0.f, 0.f, 0.f, 0.f};

  const int r_ = tid >> 3, c_ = tid & 7;             // stage: 4 A-rows + 2 B-rows, slot c_
  __syncthreads();                                   // ridx_s ready
  const float* rowp[4];
  _Float16* h16p[4];
  #pragma unroll
  for (int p = 0; p < 4; ++p) {
    rowp[p] = hsrc + ((size_t)b * S_L + ridx_s[p * 32 + r_]) * D_M + c_ * 8;
    h16p[p] = h16c + ((size_t)b * S_L + s0 + p * 32 + r_) * D_M + c_ * 8;
  }
  float4 fa[4][2];
  half8v fb[2];
  #pragma unroll
  for (int p = 0; p < 4; ++p) {
    fa[p][0] = *(const float4*)rowp[p]; fa[p][1] = *(const float4*)(rowp[p] + 4);
  }
  fb[0] = *(const half8v*)(qth + (size_t)r_ * D_M + c_ * 8);
  fb[1] = *(const half8v*)(qth + (size_t)(r_ + 32) * D_M + c_ * 8);

  for (int k0 = 0; k0 < D_M; k0 += 64) {
    __syncthreads();
    #pragma unroll
    for (int p = 0; p < 4; ++p) {
      half8v hv;
      hv[0] = (_Float16)fa[p][0].x; hv[1] = (_Float16)fa[p][0].y;
      hv[2] = (_Float16)fa[p][0].z; hv[3] = (_Float16)fa[p][0].w;
      hv[4] = (_Float16)fa[p][1].x; hv[5] = (_Float16)fa[p][1].y;
      hv[6] = (_Float16)fa[p][1].z; hv[7] = (_Float16)fa[p][1].w;
      *(half8v*)&As[(p * 32 + r_) * AP_ + c_ * 8] = hv;
      *(half8v*)(h16p[p] + k0) = hv;                 // fp16 compact side-write
    }
    *(half8v*)&Bs[r_ * AP_ + c_ * 8] = fb[0];
    *(half8v*)&Bs[(r_ + 32) * AP_ + c_ * 8] = fb[1];
    if (k0 + 64 < D_M) {
      #pragma unroll
      for (int p = 0; p < 4; ++p) {
        fa[p][0] = *(const float4*)(rowp[p] + k0 + 64);
        fa[p][1] = *(const float4*)(rowp[p] + k0 + 64 + 4);
      }
      fb[0] = *(const half8v*)(qth + (size_t)r_ * D_M + (k0 + 64) + c_ * 8);
      fb[1] = *(const half8v*)(qth + (size_t)(r_ + 32) * D_M + (k0 + 64) + c_ * 8);
    }
    __syncthreads();
    #pragma unroll
    for (int kk = 0; kk < 2; ++kk) {
      half8v af[2], bf4[4];
      #pragma unroll
      for (int mf = 0; mf < 2; ++mf)
        af[mf] = *(const half8v*)&As[(w * 32 + mf * 16 + row16) * AP_ + kk * 32 + kc * 8];
      #pragma unroll
      for (int nf = 0; nf < 4; ++nf)
        bf4[nf] = *(const half8v*)&Bs[(nf * 16 + row16) * AP_ + kk * 32 + kc * 8];
      #pragma unroll
      for (int mf = 0; mf < 2; ++mf)
        #pragma unroll
        for (int nf = 0; nf < 4; ++nf)
          acc[mf][nf] = __builtin_amdgcn_mfma_f32_16x16x32_f16(af[mf], bf4[nf], acc[mf][nf], 0, 0, 0);
    }
  }
  // ---- epilogue: valid = compact row < cnt[b]; tile max, exp into pT, pm/pl
  int msk[8];
  #pragma unroll
  for (int mf = 0; mf < 2; ++mf)
    #pragma unroll
    for (int r = 0; r < 4; ++r)
      msk[mf * 4 + r] = (s0 + w * 32 + mf * 16 + kc * 4 + r) < cb;
  #pragma unroll
  for (int nf = 0; nf < 4; ++nf) {
    int hk = nf * 16 + row16;
    float qcv = qcs[hk];
    float vals[8];
    float mloc = -3.4e38f;
    #pragma unroll
    for (int mf = 0; mf < 2; ++mf)
      #pragma unroll
      for (int r = 0; r < 4; ++r) {
        float v = msk[mf * 4 + r] ? (acc[mf][nf][r] + qcv) : NEG_INF_;
        vals[mf * 4 + r] = v;
        mloc = fmaxf(mloc, v);
      }
    mloc = fmaxf(mloc, __shfl_xor(mloc, 16, 64));
    mloc = fmaxf(mloc, __shfl_xor(mloc, 32, 64));
    float ls = 0.f;
    #pragma unroll
    for (int mf = 0; mf < 2; ++mf)
      #pragma unroll
      for (int r = 0; r < 4; ++r) {
        float e = __expf(vals[mf * 4 + r] - mloc);
        ls += e;
        pT[w * 32 + mf * 16 + kc * 4 + r][hk] = (_Float16)e;
      }
    ls += __shfl_xor(ls, 16, 64);
    ls += __shfl_xor(ls, 32, 64);
    if (kc == 0) {
      int idx = ((b * 64 + st) * 4 + w) * 64 + hk;   // tile = st*4+w (32 rows)
      pm[idx] = mloc;
      pl[idx] = ls;
    }
  }
  __syncthreads();
  // ---- coalesced ph write: thread = (hk2, s-quarter of 32)
  {
    int hk2 = tid >> 2, q4 = tid & 3;
    _Float16* dst = ph + ((size_t)b * 64 + hk2) * S_L + s0 + q4 * 32;
    #pragma unroll
    for (int i = 0; i < 4; ++i) {
      half8v v;
      #pragma unroll
      for (int e = 0; e < 8; ++e) v[e] = pT[q4 * 32 + i * 8 + e][hk2];
      *(half8v*)(dst + i * 8) = v;
    }
  }
}

// ---- per (b,hk): reduce valid tile partials -> lvinv; rescale ph by exp(m_tile - M)
// grid 512 = b*64+hk; block 256 (thread = tile of 32 rows)
__global__ __launch_bounds__(256) void k_stats2b(
    const float* __restrict__ pm, const float* __restrict__ pl,
    const int* __restrict__ cnt, float* __restrict__ lvinv, _Float16* __restrict__ ph) {
  __shared__ float red[256];
  int bh = blockIdx.x;
  int b = bh >> 6, hk = bh & 63;
  int tid = threadIdx.x;
  const int cb = cnt[b];
  const int ntile = (((cb + 511) >> 9) << 9) >> 5;   // SPb/32
  float m = -3.4e38f, lv = 0.f;
  if (tid < ntile) {
    m = pm[((size_t)b * 256 + tid) * 64 + hk];
    lv = pl[((size_t)b * 256 + tid) * 64 + hk];
  }
  red[tid] = m; __syncthreads();
  for (int off = 128; off > 0; off >>= 1) {
    if (tid < off) red[tid] = fmaxf(red[tid], red[tid + off]);
    __syncthreads();
  }
  float M = red[0]; __syncthreads();
  red[tid] = lv * __expf(m - M); __syncthreads();
  for (int off = 128; off > 0; off >>= 1) {
    if (tid < off) red[tid] += red[tid + off];
    __syncthreads();
  }
  if (tid == 0) lvinv[bh] = 1.f / red[0];
  if (tid < ntile) {
    float f = __expf(m - M);
    _Float16* pp = ph + (size_t)bh * S_L + tid * 32;
    #pragma unroll
    for (int i = 0; i < 4; ++i) {
      half8v v = *(half8v*)(pp + i * 8);
      #pragma unroll
      for (int e = 0; e < 8; ++e) v[e] = (_Float16)((float)v[e] * f);
      *(half8v*)(pp + i * 8) = v;
    }
  }
}

// ---- PV via MFMA on COMPACT fp16 rows: part[b][jb][sc][hk][512], sc chunks of 256
// grid 512 = b(8) x jb(2) x sc(32 of 256 s); block 512 (8 waves). Early-exit past SPb.
__global__ __launch_bounds__(512) void k_part(
    const _Float16* __restrict__ h16c, const _Float16* __restrict__ ph,
    const int* __restrict__ cnt, float* __restrict__ part) {
  __shared__ __align__(16) _Float16 htile[512 * PITCH_];   // 40 KB
  const int tid = threadIdx.x;
  const int b  = blockIdx.x >> 6;
  const int jb = (blockIdx.x >> 5) & 1;
  const int sc = blockIdx.x & 31;
  const int SPb = ((cnt[b] + 511) >> 9) << 9;
  if (sc * 256 >= SPb) return;                       // uniform early exit
  const int w = tid >> 6, l = tid & 63;
  const int row16 = l & 15, kc = l >> 4;
  const int s_base = sc * 256;
  const _Float16* hb = h16c + (size_t)b * S_L * D_M + jb * 512;
  const _Float16* phb = ph + (size_t)b * HK_ * S_L;
  floatx4 acc[4][4];
  #pragma unroll
  for (int mf = 0; mf < 4; ++mf)
    #pragma unroll
    for (int nf = 0; nf < 4; ++nf) acc[mf][nf] = (floatx4){0.f, 0.f, 0.f, 0.f};

  const int jcol = tid;
  _Float16 colv[32];
  #pragma unroll
  for (int s = 0; s < 32; ++s)
    colv[s] = hb[(size_t)(s_base + s) * D_M + jcol];

  for (int t = 0; t < 8; ++t) {
    const int s0 = s_base + t * 32;
    __syncthreads();
    #pragma unroll
    for (int sb = 0; sb < 8; ++sb) {
      half4v hv;
      hv[0] = colv[sb * 4 + 0];
      hv[1] = colv[sb * 4 + 1];
      hv[2] = colv[sb * 4 + 2];
      hv[3] = colv[sb * 4 + 3];
      *(half4v*)&htile[jcol * PITCH_ + sb * 4] = hv;
    }
    __syncthreads();
    if (t < 7) {
      #pragma unroll
      for (int s = 0; s < 32; ++s)
        colv[s] = hb[(size_t)(s0 + 32 + s) * D_M + jcol];
    }
    half8v ap[4];
    #pragma unroll
    for (int mf = 0; mf < 4; ++mf)
      ap[mf] = *(const half8v*)(phb + (size_t)(mf * 16 + row16) * S_L + s0 + kc * 8);
    #pragma unroll
    for (int nf = 0; nf < 4; ++nf) {
      int j = w * 64 + nf * 16 + row16;
      half8v bv = *(const half8v*)&htile[j * PITCH_ + kc * 8];
      #pragma unroll
      for (int mf = 0; mf < 4; ++mf)
        acc[mf][nf] = __builtin_amdgcn_mfma_f32_16x16x32_f16(ap[mf], bv, acc[mf][nf], 0, 0, 0);
    }
  }
  #pragma unroll
  for (int mf = 0; mf < 4; ++mf)
    #pragma unroll
    for (int nf = 0; nf < 4; ++nf) {
      int j = w * 64 + nf * 16 + row16;
      #pragma unroll
      for (int r = 0; r < 4; ++r) {
        int hk = mf * 16 + kc * 4 + r;
        part[(((size_t)(b * 2 + jb) * 32 + sc) * HK_ + hk) * 512 + j] = acc[mf][nf][r];
      }
    }
}

// ---- ctxh[b][hk][j] = (sum over valid sc) part * lvinv
__global__ void k_comb(const float* __restrict__ part, const float* __restrict__ lvinv,
                       const int* __restrict__ cnt, float* __restrict__ ctxh) {
  int g = blockIdx.x * blockDim.x + threadIdx.x;  // 131072 float4s
  int b = g >> 14;
  int rem = g & 16383;
  int hk = rem >> 8;
  int j4 = rem & 255;
  int jb = j4 >> 7;
  int jr4 = j4 & 127;
  const int nsc = (((cnt[b] + 511) >> 9) << 9) >> 8;   // SPb/256
  const float* pb = part + ((size_t)(b * 2 + jb) * 32 * HK_ + hk) * 512 + jr4 * 4;
  float4 s = make_float4(0.f, 0.f, 0.f, 0.f);
  for (int sc = 0; sc < nsc; ++sc) {
    float4 v = *(const float4*)(pb + (size_t)sc * HK_ * 512);
    s.x += v.x; s.y += v.y; s.z += v.z; s.w += v.w;
  }
  float li = lvinv[b * 64 + hk];
  s.x *= li; s.y *= li; s.z *= li; s.w *= li;
  *(float4*)(ctxh + ((size_t)b * HK_ + hk) * D_M + j4 * 4) = s;
}

// ---- ctx[b][kidx][i] = Wv[i].ctxh[b][hk(i,kidx)] + bv[i]  (4-way split-K)
__global__ void k_ctx(const float* __restrict__ ctxh, const float* __restrict__ W,
                      const float* __restrict__ bias, float* __restrict__ ctx) {
  int g2 = blockIdx.x * blockDim.x + threadIdx.x;   // 262144
  int o = g2 >> 2, kq = g2 & 3;
  int b = o >> 13, kidx = (o >> 10) & 7, i = o & 1023;
  int hk = (i >> 7) * 8 + kidx;
  const float* wr = W + ((size_t)2 * D_M + i) * D_M + kq * 256;
  const float* xr = ctxh + ((size_t)b * HK_ + hk) * D_M + kq * 256;
  float acc = 0.f;
  #pragma unroll 8
  for (int t = 0; t < 256; t += 4) {
    float4 w = *(const float4*)(wr + t);
    float4 x = *(const float4*)(xr + t);
    acc += w.x*x.x + w.y*x.y + w.z*x.z + w.w*x.w;
  }
  acc += __shfl_xor(acc, 1, 64);
  acc += __shfl_xor(acc, 2, 64);
  if (kq == 0) ctx[o] = acc + bias[2 * D_M + i];
}

// ---- pooled[b][kidx][i] = Wout[i].ctx[b][kidx] + bo[i]  (4-way split-K)
__global__ void k_pool(const float* __restrict__ ctx, const float* __restrict__ W,
                       const float* __restrict__ bias, float* __restrict__ pooled) {
  int g2 = blockIdx.x * blockDim.x + threadIdx.x;   // 262144
  int o = g2 >> 2, kq = g2 & 3;
  int b = o >> 13, kidx = (o >> 10) & 7, i = o & 1023;
  const float* wr = W + (size_t)i * D_M + kq * 256;
  const float* xr = ctx + ((size_t)b * 8 + kidx) * D_M + kq * 256;
  float acc = 0.f;
  #pragma unroll 8
  for (int t = 0; t < 256; t += 4) {
    float4 w = *(const float4*)(wr + t);
    float4 x = *(const float4*)(xr + t);
    acc += w.x*x.x + w.y*x.y + w.z*x.z + w.w*x.w;
  }
  acc += __shfl_xor(acc, 1, 64);
  acc += __shfl_xor(acc, 2, 64);
  if (kq == 0) pooled[o] = acc + bias[i];
}

// ---- LayerNorm per (b,kidx) then mean over kidx -> out[b][i]
__global__ void k_ln(const float* __restrict__ pooled, const float* __restrict__ gamma,
                     const float* __restrict__ beta, float* __restrict__ out) {
  __shared__ float red[256];
  int b = blockIdx.x, tid = threadIdx.x;
  float acc[4] = {0.f, 0.f, 0.f, 0.f};
  for (int kidx = 0; kidx < 8; ++kidx) {
    const float* row = pooled + ((size_t)b * 8 + kidx) * D_M;
    float v[4]; float s = 0.f;
    #pragma unroll
    for (int c = 0; c < 4; ++c) { v[c] = row[tid + 256 * c]; s += v[c]; }
    red[tid] = s; __syncthreads();
    for (int off = 128; off > 0; off >>= 1) {
      if (tid < off) red[tid] += red[tid + off];
      __syncthreads();
    }
    float mu = red[0] * (1.f / 1024.f);
    __syncthreads();
    float ss = 0.f;
    #pragma unroll
    for (int c = 0; c < 4; ++c) { float dd = v[c] - mu; ss += dd * dd; }
    red[tid] = ss; __syncthreads();
    for (int off = 128; off > 0; off >>= 1) {
      if (tid < off) red[tid] += red[tid + off];
      __syncthreads();
    }
    float rstd = rsqrtf(red[0] * (1.f / 1024.f) + 1e-5f);
    __syncthreads();
    #pragma unroll
    for (int c = 0; c < 4; ++c) {
      int i = tid + 256 * c;
      acc[c] += ((v[c] - mu) * rstd * gamma[i] + beta[i]) * 0.125f;
    }
  }
  #pragma unroll
  for (int c = 0; c < 4; ++c) out[(size_t)b * D_M + tid + 256 * c] = acc[c];
}

extern "C" void kernel_launch(void* const* d_in, const int* in_sizes, int n_in,
                              void* d_out, int out_size, void* d_ws, size_t ws_size,
                              hipStream_t stream) {
  const float* hidden = (const float*)d_in[0];
  const float* latent = (const float*)d_in[1];
  const float* w_in   = (const float*)d_in[2];
  const float* b_in   = (const float*)d_in[3];
  const float* w_out  = (const float*)d_in[4];
  const float* b_out  = (const float*)d_in[5];
  const float* gamma  = (const float*)d_in[6];
  const float* beta   = (const float*)d_in[7];
  const int*   mask   = (const int*)d_in[8];
  float* out = (float*)d_out;
  float* ws = (float*)d_ws;
  // workspace layout (floats): ~215 MB total
  float* q      = ws;                       // 8192
  float* qc     = q + 8192;                 // 64
  float* lvinv  = qc + 64;                  // 512
  float* pm     = lvinv + 512;              // 131072 = [8][256][64]
  float* pl     = pm + 131072;              // 131072
  _Float16* qth = (_Float16*)(pl + 131072);          // 65536 halves (32768 float slots)
  _Float16* ph  = (_Float16*)(pl + 131072 + 32768);  // 4194304 halves (2097152 slots)
  float* part   = pl + 131072 + 32768 + 2097152;     // 16777216 = [8][2][32][64][512]
  float* ctxh   = part + 16777216;          // 524288
  float* ctx    = ctxh + 524288;            // 65536
  float* pooled = ctx + 65536;              // 65536
  int*   cnt    = (int*)(pooled + 65536);   // 16 ints
  int*   ridx   = (int*)(pooled + 65536 + 16);        // 65536 ints
  _Float16* h16c = (_Float16*)(pooled + 65536 + 16 + 65536);  // 67108864 halves (128 MB)

  k_q       <<<32,   256, 0, stream>>>(latent, w_in, b_in, q);
  k_qt      <<<256,  256, 0, stream>>>(q, w_in, b_in, qth, qc);
  k_cnt     <<<8,    512, 0, stream>>>(mask, ridx, cnt);
  k_scores3 <<<512,  256, 0, stream>>>(hidden, qth, qc, cnt, ridx, h16c, ph, pm, pl);
  k_stats2b <<<512,  256, 0, stream>>>(pm, pl, cnt, lvinv, ph);
  k_part    <<<512,  512, 0, stream>>>(h16c, ph, cnt, part);
  k_comb    <<<512,  256, 0, stream>>>(part, lvinv, cnt, ctxh);
  k_ctx     <<<1024, 256, 0, stream>>>(ctxh, w_in, b_in, ctx);
  k_pool    <<<1024, 256, 0, stream>>>(ctx, w_out, b_out, pooled);
  k_ln      <<<8,    256, 0, stream>>>(pooled, gamma, beta, out);
}

// Round 17
// 309.967 us; speedup vs baseline: 1.0485x; 1.0473x over previous
//
#include <hip/hip_runtime.h>
#include <math.h>

#define D_M 1024
#define S_L 8192
#define B_N 8
#define H_N 8
#define HD_ 128
#define HK_ 64
#define SCALE_ 0.08838834764831845f
#define NEG_INF_ -1e9f
#define PITCH_ 40   // k_part transposed tile pitch (halves): 80B, 16B-aligned
#define AP_ 72      // k_scores3 As/Bs pitch (halves): 144B -> balanced banks, 16B-aligned

typedef _Float16 half8v __attribute__((ext_vector_type(8)));
typedef _Float16 half4v __attribute__((ext_vector_type(4)));
typedef float floatx4 __attribute__((ext_vector_type(4)));

// ---- q[kidx][i] = latent[kidx] . Wq[i] + bq[i]   (8x1024)
__global__ void k_q(const float* __restrict__ lat, const float* __restrict__ W,
                    const float* __restrict__ bias, float* __restrict__ q) {
  int g = blockIdx.x * blockDim.x + threadIdx.x;          // 8192
  int kidx = g >> 10, i = g & 1023;
  const float* wr = W + (size_t)i * D_M;
  const float* lr = lat + kidx * D_M;
  float acc = bias[i];
  #pragma unroll 4
  for (int t = 0; t < D_M; t += 4) {
    float4 w = *(const float4*)(wr + t);
    float4 l = *(const float4*)(lr + t);
    acc += w.x*l.x + w.y*l.y + w.z*l.z + w.w*l.w;
  }
  q[g] = acc;
}

// ---- qth[hk][j] = fp16( SCALE * sum_dd q[kidx][h*128+dd] * Wk[h*128+dd][j] ); qconst[hk]
__global__ void k_qt(const float* __restrict__ q, const float* __restrict__ W,
                     const float* __restrict__ bias, _Float16* __restrict__ qth,
                     float* __restrict__ qconst) {
  int g = blockIdx.x * blockDim.x + threadIdx.x;          // 65536
  int hk = g >> 10, j = g & 1023;
  int h = hk >> 3, kidx = hk & 7;
  const float* qr = q + kidx * D_M + h * HD_;
  const float* wb = W + ((size_t)D_M + (size_t)h * HD_) * D_M + j;
  float acc = 0.f;
  #pragma unroll 4
  for (int dd = 0; dd < HD_; ++dd)
    acc += qr[dd] * wb[(size_t)dd * D_M];
  qth[g] = (_Float16)(acc * SCALE_);
  if (j == 0) {
    const float* bk = bias + D_M + h * HD_;
    float c = 0.f;
    for (int dd = 0; dd < HD_; ++dd) c += qr[dd] * bk[dd];
    qconst[hk] = c * SCALE_;
  }
}

// ---- per b: compact row map ridx[b][slot] = orig s (stable order), cnt[b].
// grid 8, block 512. Deterministic. Pad slots -> 0 (finite data, ph=0 kills them).
__global__ __launch_bounds__(512) void k_cnt(const int* __restrict__ mask,
                                             int* __restrict__ ridx,
                                             int* __restrict__ cnt) {
  __shared__ int wsum[8];
  __shared__ int base_s;
  int b = blockIdx.x, tid = threadIdx.x, w = tid >> 6, lane = tid & 63;
  #pragma unroll
  for (int it = 0; it < 16; ++it) ridx[b * S_L + it * 512 + tid] = 0;
  if (tid == 0) base_s = 0;
  __syncthreads();
  for (int it = 0; it < 16; ++it) {
    int s = it * 512 + tid;
    int valid = mask[b * S_L + s] != 0;
    unsigned long long m = __ballot(valid);
    int rank = __popcll(m & ((1ull << lane) - 1ull));
    if (lane == 0) wsum[w] = __popcll(m);
    __syncthreads();                       // wsum ready
    int base = base_s;
    int woff = 0, ctot = 0;
    #pragma unroll
    for (int i = 0; i < 8; ++i) { if (i < w) woff += wsum[i]; ctot += wsum[i]; }
    __syncthreads();                       // all read base_s
    if (valid) ridx[b * S_L + base + woff + rank] = s;
    if (tid == 0) base_s = base + ctot;
    __syncthreads();                       // base_s updated
  }
  if (tid == 0) cnt[b] = base_s;
}

// ---- QK^T via MFMA on COMPACT rows (indirect stage through ridx), BK=64.
//      Side-writes fp16 compact h16c; emits ph = exp(v - m_tile32), pm/pl.
// grid 512 = b(8) x st(64 of 128 rows); block 256 (4 waves). Early-exit past SPb.
__global__ __launch_bounds__(256) void k_scores3(
    const float* __restrict__ hsrc, const _Float16* __restrict__ qth,
    const float* __restrict__ qc, const int* __restrict__ cnt,
    const int* __restrict__ ridx, _Float16* __restrict__ h16c,
    _Float16* __restrict__ ph, float* __restrict__ pm, float* __restrict__ pl) {
  __shared__ __align__(16) _Float16 As[128 * AP_];   // 18 KB
  __shared__ __align__(16) _Float16 Bs[64 * AP_];    // 9 KB
  __shared__ _Float16 pT[128][68];                   // 17 KB (transpose buffer)
  __shared__ float qcs[64];
  __shared__ int ridx_s[128];
  const int tid = threadIdx.x;
  const int b = blockIdx.x >> 6;
  const int st = blockIdx.x & 63;
  const int s0 = st * 128;
  const int cb = cnt[b];
  const int SPb = ((cb + 511) >> 9) << 9;
  if (s0 >= SPb) return;                             // uniform early exit
  const int w = tid >> 6, l = tid & 63;
  const int row16 = l & 15, kc = l >> 4;
  if (tid < 64) qcs[tid] = qc[tid];
  if (tid < 128) ridx_s[tid] = ridx[b * S_L + s0 + tid];
  floatx4 acc[2][4];
  #pragma unroll
  for (int mf = 0; mf < 2; ++mf)
    #pragma unroll
    for (int nf = 0; nf < 4; ++nf) acc[mf][nf] = (floatx4){0.f, 0.f, 0.f, 0.f};

  const int r_ = tid >> 3, c_ = tid & 7;             // stage: 4 A-rows + 2 B-rows, slot c_
  __syncthreads();                                   // ridx_s ready
  const float* rowp[4];
  _Float16* h16p[4];
  #pragma unroll
  for (int p = 0; p < 4; ++p) {
    rowp[p] = hsrc + ((size_t)b * S_L + ridx_s[p * 32 + r_]) * D_M + c_ * 8;
    h16p[p] = h16c + ((size_t)b * S_L + s0 + p * 32 + r_) * D_M + c_ * 8;
  }
  float4 fa[4][2];
  half8v fb[2];
  #pragma unroll
  for (int p = 0; p < 4; ++p) {
    fa[p][0] = *(const float4*)rowp[p]; fa[p][1] = *(const float4*)(rowp[p] + 4);
  }
  fb[0] = *(const half8v*)(qth + (size_t)r_ * D_M + c_ * 8);
  fb[1] = *(const half8v*)(qth + (size_t)(r_ + 32) * D_M + c_ * 8);

  for (int k0 = 0; k0 < D_M; k0 += 64) {
    __syncthreads();
    #pragma unroll
    for (int p = 0; p < 4; ++p) {
      half8v hv;
      hv[0] = (_Float16)fa[p][0].x; hv[1] = (_Float16)fa[p][0].y;
      hv[2] = (_Float16)fa[p][0].z; hv[3] = (_Float16)fa[p][0].w;
      hv[4] = (_Float16)fa[p][1].x; hv[5] = (_Float16)fa[p][1].y;
      hv[6] = (_Float16)fa[p][1].z; hv[7] = (_Float16)fa[p][1].w;
      *(half8v*)&As[(p * 32 + r_) * AP_ + c_ * 8] = hv;
      *(half8v*)(h16p[p] + k0) = hv;                 // fp16 compact side-write
    }
    *(half8v*)&Bs[r_ * AP_ + c_ * 8] = fb[0];
    *(half8v*)&Bs[(r_ + 32) * AP_ + c_ * 8] = fb[1];
    if (k0 + 64 < D_M) {
      #pragma unroll
      for (int p = 0; p < 4; ++p) {
        fa[p][0] = *(const float4*)(rowp[p] + k0 + 64);
        fa[p][1] = *(const float4*)(rowp[p] + k0 + 64 + 4);
      }
      fb[0] = *(const half8v*)(qth + (size_t)r_ * D_M + (k0 + 64) + c_ * 8);
      fb[1] = *(const half8v*)(qth + (size_t)(r_ + 32) * D_M + (k0 + 64) + c_ * 8);
    }
    __syncthreads();
    #pragma unroll
    for (int kk = 0; kk < 2; ++kk) {
      half8v af[2], bf4[4];
      #pragma unroll
      for (int mf = 0; mf < 2; ++mf)
        af[mf] = *(const half8v*)&As[(w * 32 + mf * 16 + row16) * AP_ + kk * 32 + kc * 8];
      #pragma unroll
      for (int nf = 0; nf < 4; ++nf)
        bf4[nf] = *(const half8v*)&Bs[(nf * 16 + row16) * AP_ + kk * 32 + kc * 8];
      #pragma unroll
      for (int mf = 0; mf < 2; ++mf)
        #pragma unroll
        for (int nf = 0; nf < 4; ++nf)
          acc[mf][nf] = __builtin_amdgcn_mfma_f32_16x16x32_f16(af[mf], bf4[nf], acc[mf][nf], 0, 0, 0);
    }
  }
  // ---- epilogue: valid = compact row < cnt[b]; tile max, exp into pT, pm/pl
  int msk[8];
  #pragma unroll
  for (int mf = 0; mf < 2; ++mf)
    #pragma unroll
    for (int r = 0; r < 4; ++r)
      msk[mf * 4 + r] = (s0 + w * 32 + mf * 16 + kc * 4 + r) < cb;
  #pragma unroll
  for (int nf = 0; nf < 4; ++nf) {
    int hk = nf * 16 + row16;
    float qcv = qcs[hk];
    float vals[8];
    float mloc = -3.4e38f;
    #pragma unroll
    for (int mf = 0; mf < 2; ++mf)
      #pragma unroll
      for (int r = 0; r < 4; ++r) {
        float v = msk[mf * 4 + r] ? (acc[mf][nf][r] + qcv) : NEG_INF_;
        vals[mf * 4 + r] = v;
        mloc = fmaxf(mloc, v);
      }
    mloc = fmaxf(mloc, __shfl_xor(mloc, 16, 64));
    mloc = fmaxf(mloc, __shfl_xor(mloc, 32, 64));
    float ls = 0.f;
    #pragma unroll
    for (int mf = 0; mf < 2; ++mf)
      #pragma unroll
      for (int r = 0; r < 4; ++r) {
        float e = __expf(vals[mf * 4 + r] - mloc);
        ls += e;
        pT[w * 32 + mf * 16 + kc * 4 + r][hk] = (_Float16)e;
      }
    ls += __shfl_xor(ls, 16, 64);
    ls += __shfl_xor(ls, 32, 64);
    if (kc == 0) {
      int idx = ((b * 64 + st) * 4 + w) * 64 + hk;   // tile = st*4+w (32 rows)
      pm[idx] = mloc;
      pl[idx] = ls;
    }
  }
  __syncthreads();
  // ---- coalesced ph write: thread = (hk2, s-quarter of 32)
  {
    int hk2 = tid >> 2, q4 = tid & 3;
    _Float16* dst = ph + ((size_t)b * 64 + hk2) * S_L + s0 + q4 * 32;
    #pragma unroll
    for (int i = 0; i < 4; ++i) {
      half8v v;
      #pragma unroll
      for (int e = 0; e < 8; ++e) v[e] = pT[q4 * 32 + i * 8 + e][hk2];
      *(half8v*)(dst + i * 8) = v;
    }
  }
}

// ---- per (b,hk): reduce valid tile partials -> lvinv; rescale ph by exp(m_tile - M)
// grid 512 = b*64+hk; block 256 (thread = tile of 32 rows)
__global__ __launch_bounds__(256) void k_stats2b(
    const float* __restrict__ pm, const float* __restrict__ pl,
    const int* __restrict__ cnt, float* __restrict__ lvinv, _Float16* __restrict__ ph) {
  __shared__ float red[256];
  int bh = blockIdx.x;
  int b = bh >> 6, hk = bh & 63;
  int tid = threadIdx.x;
  const int cb = cnt[b];
  const int ntile = (((cb + 511) >> 9) << 9) >> 5;   // SPb/32
  float m = -3.4e38f, lv = 0.f;
  if (tid < ntile) {
    m = pm[((size_t)b * 256 + tid) * 64 + hk];
    lv = pl[((size_t)b * 256 + tid) * 64 + hk];
  }
  red[tid] = m; __syncthreads();
  for (int off = 128; off > 0; off >>= 1) {
    if (tid < off) red[tid] = fmaxf(red[tid], red[tid + off]);
    __syncthreads();
  }
  float M = red[0]; __syncthreads();
  red[tid] = lv * __expf(m - M); __syncthreads();
  for (int off = 128; off > 0; off >>= 1) {
    if (tid < off) red[tid] += red[tid + off];
    __syncthreads();
  }
  if (tid == 0) lvinv[bh] = 1.f / red[0];
  if (tid < ntile) {
    float f = __expf(m - M);
    _Float16* pp = ph + (size_t)bh * S_L + tid * 32;
    #pragma unroll
    for (int i = 0; i < 4; ++i) {
      half8v v = *(half8v*)(pp + i * 8);
      #pragma unroll
      for (int e = 0; e < 8; ++e) v[e] = (_Float16)((float)v[e] * f);
      *(half8v*)(pp + i * 8) = v;
    }
  }
}

// ---- PV via MFMA on COMPACT fp16 rows: part[b][jb][sc][hk][512]
// grid 256 = b(8) x jb(2) x sc(16 of 512 s); block 512 (8 waves). Early-exit empty chunks.
__global__ __launch_bounds__(512) void k_part(
    const _Float16* __restrict__ h16c, const _Float16* __restrict__ ph,
    const int* __restrict__ cnt, float* __restrict__ part) {
  __shared__ __align__(16) _Float16 htile[512 * PITCH_];   // 40 KB
  const int tid = threadIdx.x;
  const int b  = blockIdx.x >> 5;
  const int jb = (blockIdx.x >> 4) & 1;
  const int sc = blockIdx.x & 15;
  const int SPb = ((cnt[b] + 511) >> 9) << 9;
  if (sc * 512 >= SPb) return;                       // uniform early exit
  const int w = tid >> 6, l = tid & 63;
  const int row16 = l & 15, kc = l >> 4;
  const int s_base = sc * 512;
  const _Float16* hb = h16c + (size_t)b * S_L * D_M + jb * 512;
  const _Float16* phb = ph + (size_t)b * HK_ * S_L;
  floatx4 acc[4][4];
  #pragma unroll
  for (int mf = 0; mf < 4; ++mf)
    #pragma unroll
    for (int nf = 0; nf < 4; ++nf) acc[mf][nf] = (floatx4){0.f, 0.f, 0.f, 0.f};

  const int jcol = tid;
  _Float16 colv[32];
  #pragma unroll
  for (int s = 0; s < 32; ++s)
    colv[s] = hb[(size_t)(s_base + s) * D_M + jcol];

  for (int t = 0; t < 16; ++t) {
    const int s0 = s_base + t * 32;
    __syncthreads();
    #pragma unroll
    for (int sb = 0; sb < 8; ++sb) {
      half4v hv;
      hv[0] = colv[sb * 4 + 0];
      hv[1] = colv[sb * 4 + 1];
      hv[2] = colv[sb * 4 + 2];
      hv[3] = colv[sb * 4 + 3];
      *(half4v*)&htile[jcol * PITCH_ + sb * 4] = hv;
    }
    __syncthreads();
    if (t < 15) {
      #pragma unroll
      for (int s = 0; s < 32; ++s)
        colv[s] = hb[(size_t)(s0 + 32 + s) * D_M + jcol];
    }
    half8v ap[4];
    #pragma unroll
    for (int mf = 0; mf < 4; ++mf)
      ap[mf] = *(const half8v*)(phb + (size_t)(mf * 16 + row16) * S_L + s0 + kc * 8);
    #pragma unroll
    for (int nf = 0; nf < 4; ++nf) {
      int j = w * 64 + nf * 16 + row16;
      half8v bv = *(const half8v*)&htile[j * PITCH_ + kc * 8];
      #pragma unroll
      for (int mf = 0; mf < 4; ++mf)
        acc[mf][nf] = __builtin_amdgcn_mfma_f32_16x16x32_f16(ap[mf], bv, acc[mf][nf], 0, 0, 0);
    }
  }
  #pragma unroll
  for (int mf = 0; mf < 4; ++mf)
    #pragma unroll
    for (int nf = 0; nf < 4; ++nf) {
      int j = w * 64 + nf * 16 + row16;
      #pragma unroll
      for (int r = 0; r < 4; ++r) {
        int hk = mf * 16 + kc * 4 + r;
        part[(((size_t)(b * 2 + jb) * 16 + sc) * HK_ + hk) * 512 + j] = acc[mf][nf][r];
      }
    }
}

// ---- ctxh[b][hk][j] = (sum over valid sc) part * lvinv
__global__ void k_comb(const float* __restrict__ part, const float* __restrict__ lvinv,
                       const int* __restrict__ cnt, float* __restrict__ ctxh) {
  int g = blockIdx.x * blockDim.x + threadIdx.x;  // 131072 float4s
  int b = g >> 14;
  int rem = g & 16383;
  int hk = rem >> 8;
  int j4 = rem & 255;
  int jb = j4 >> 7;
  int jr4 = j4 & 127;
  const int nsc = (((cnt[b] + 511) >> 9) << 9) >> 9;
  const float* pb = part + ((size_t)(b * 2 + jb) * 16 * HK_ + hk) * 512 + jr4 * 4;
  float4 s = make_float4(0.f, 0.f, 0.f, 0.f);
  for (int sc = 0; sc < nsc; ++sc) {
    float4 v = *(const float4*)(pb + (size_t)sc * HK_ * 512);
    s.x += v.x; s.y += v.y; s.z += v.z; s.w += v.w;
  }
  float li = lvinv[b * 64 + hk];
  s.x *= li; s.y *= li; s.z *= li; s.w *= li;
  *(float4*)(ctxh + ((size_t)b * HK_ + hk) * D_M + j4 * 4) = s;
}

// ---- ctx[b][kidx][i] = Wv[i].ctxh[b][hk(i,kidx)] + bv[i]  (4-way split-K)
__global__ void k_ctx(const float* __restrict__ ctxh, const float* __restrict__ W,
                      const float* __restrict__ bias, float* __restrict__ ctx) {
  int g2 = blockIdx.x * blockDim.x + threadIdx.x;   // 262144
  int o = g2 >> 2, kq = g2 & 3;
  int b = o >> 13, kidx = (o >> 10) & 7, i = o & 1023;
  int hk = (i >> 7) * 8 + kidx;
  const float* wr = W + ((size_t)2 * D_M + i) * D_M + kq * 256;
  const float* xr = ctxh + ((size_t)b * HK_ + hk) * D_M + kq * 256;
  float acc = 0.f;
  #pragma unroll 8
  for (int t = 0; t < 256; t += 4) {
    float4 w = *(const float4*)(wr + t);
    float4 x = *(const float4*)(xr + t);
    acc += w.x*x.x + w.y*x.y + w.z*x.z + w.w*x.w;
  }
  acc += __shfl_xor(acc, 1, 64);
  acc += __shfl_xor(acc, 2, 64);
  if (kq == 0) ctx[o] = acc + bias[2 * D_M + i];
}

// ---- pooled[b][kidx][i] = Wout[i].ctx[b][kidx] + bo[i]  (4-way split-K)
__global__ void k_pool(const float* __restrict__ ctx, const float* __restrict__ W,
                       const float* __restrict__ bias, float* __restrict__ pooled) {
  int g2 = blockIdx.x * blockDim.x + threadIdx.x;   // 262144
  int o = g2 >> 2, kq = g2 & 3;
  int b = o >> 13, kidx = (o >> 10) & 7, i = o & 1023;
  const float* wr = W + (size_t)i * D_M + kq * 256;
  const float* xr = ctx + ((size_t)b * 8 + kidx) * D_M + kq * 256;
  float acc = 0.f;
  #pragma unroll 8
  for (int t = 0; t < 256; t += 4) {
    float4 w = *(const float4*)(wr + t);
    float4 x = *(const float4*)(xr + t);
    acc += w.x*x.x + w.y*x.y + w.z*x.z + w.w*x.w;
  }
  acc += __shfl_xor(acc, 1, 64);
  acc += __shfl_xor(acc, 2, 64);
  if (kq == 0) pooled[o] = acc + bias[i];
}

// ---- LayerNorm per (b,kidx) then mean over kidx -> out[b][i]
__global__ void k_ln(const float* __restrict__ pooled, const float* __restrict__ gamma,
                     const float* __restrict__ beta, float* __restrict__ out) {
  __shared__ float red[256];
  int b = blockIdx.x, tid = threadIdx.x;
  float acc[4] = {0.f, 0.f, 0.f, 0.f};
  for (int kidx = 0; kidx < 8; ++kidx) {
    const float* row = pooled + ((size_t)b * 8 + kidx) * D_M;
    float v[4]; float s = 0.f;
    #pragma unroll
    for (int c = 0; c < 4; ++c) { v[c] = row[tid + 256 * c]; s += v[c]; }
    red[tid] = s; __syncthreads();
    for (int off = 128; off > 0; off >>= 1) {
      if (tid < off) red[tid] += red[tid + off];
      __syncthreads();
    }
    float mu = red[0] * (1.f / 1024.f);
    __syncthreads();
    float ss = 0.f;
    #pragma unroll
    for (int c = 0; c < 4; ++c) { float dd = v[c] - mu; ss += dd * dd; }
    red[tid] = ss; __syncthreads();
    for (int off = 128; off > 0; off >>= 1) {
      if (tid < off) red[tid] += red[tid + off];
      __syncthreads();
    }
    float rstd = rsqrtf(red[0] * (1.f / 1024.f) + 1e-5f);
    __syncthreads();
    #pragma unroll
    for (int c = 0; c < 4; ++c) {
      int i = tid + 256 * c;
      acc[c] += ((v[c] - mu) * rstd * gamma[i] + beta[i]) * 0.125f;
    }
  }
  #pragma unroll
  for (int c = 0; c < 4; ++c) out[(size_t)b * D_M + tid + 256 * c] = acc[c];
}

extern "C" void kernel_launch(void* const* d_in, const int* in_sizes, int n_in,
                              void* d_out, int out_size, void* d_ws, size_t ws_size,
                              hipStream_t stream) {
  const float* hidden = (const float*)d_in[0];
  const float* latent = (const float*)d_in[1];
  const float* w_in   = (const float*)d_in[2];
  const float* b_in   = (const float*)d_in[3];
  const float* w_out  = (const float*)d_in[4];
  const float* b_out  = (const float*)d_in[5];
  const float* gamma  = (const float*)d_in[6];
  const float* beta   = (const float*)d_in[7];
  const int*   mask   = (const int*)d_in[8];
  float* out = (float*)d_out;
  float* ws = (float*)d_ws;
  // workspace layout (floats): ~180 MB total
  float* q      = ws;                       // 8192
  float* qc     = q + 8192;                 // 64
  float* lvinv  = qc + 64;                  // 512
  float* pm     = lvinv + 512;              // 131072 = [8][256][64]
  float* pl     = pm + 131072;              // 131072
  _Float16* qth = (_Float16*)(pl + 131072);          // 65536 halves (32768 float slots)
  _Float16* ph  = (_Float16*)(pl + 131072 + 32768);  // 4194304 halves (2097152 slots)
  float* part   = pl + 131072 + 32768 + 2097152;     // 8388608 = [8][2][16][64][512]
  float* ctxh   = part + 8388608;           // 524288
  float* ctx    = ctxh + 524288;            // 65536
  float* pooled = ctx + 65536;              // 65536
  int*   cnt    = (int*)(pooled + 65536);   // 16 ints
  int*   ridx   = (int*)(pooled + 65536 + 16);        // 65536 ints
  _Float16* h16c = (_Float16*)(pooled + 65536 + 16 + 65536);  // 67108864 halves (128 MB)

  k_q       <<<32,   256, 0, stream>>>(latent, w_in, b_in, q);
  k_qt      <<<256,  256, 0, stream>>>(q, w_in, b_in, qth, qc);
  k_cnt     <<<8,    512, 0, stream>>>(mask, ridx, cnt);
  k_scores3 <<<512,  256, 0, stream>>>(hidden, qth, qc, cnt, ridx, h16c, ph, pm, pl);
  k_stats2b <<<512,  256, 0, stream>>>(pm, pl, cnt, lvinv, ph);
  k_part    <<<256,  512, 0, stream>>>(h16c, ph, cnt, part);
  k_comb    <<<512,  256, 0, stream>>>(part, lvinv, cnt, ctxh);
  k_ctx     <<<1024, 256, 0, stream>>>(ctxh, w_in, b_in, ctx);
  k_pool    <<<1024, 256, 0, stream>>>(ctx, w_out, b_out, pooled);
  k_ln      <<<8,    256, 0, stream>>>(pooled, gamma, beta, out);
}